// Round 10
// baseline (508.679 us; speedup 1.0000x reference)
//
#include <hip/hip_runtime.h>

typedef _Float16 half8 __attribute__((ext_vector_type(8)));
typedef _Float16 half4 __attribute__((ext_vector_type(4)));
typedef __fp16 fp16x2 __attribute__((ext_vector_type(2)));
typedef float f32x4 __attribute__((ext_vector_type(4)));

#define SELU_SCALE 1.0507009873554805f
#define SELU_ALPHA 1.6732632423543772f
#define LOG2E 1.4426950408889634f
#define LN2f 0.6931471805599453f
#define CA (SELU_ALPHA * LOG2E)

// ---- LDS: fragment-linear weights (conflict-free contiguous reads) ----
// b64 frag slot = (frag*64 + lane)*8 ; b128 slot = (frag*64 + lane)*16
#define W1F 0        // [8mt][2kt][64]  half4 = 8192 B
#define W2F 8192     // [8mt][8kt][64]  half4 = 32768 B
#define W3F 40960    // [2mt][8kt][64]  half4 = 8192 B
#define W0F 49152    // [2mt][64]       half8 = 2048 B
#define W4F 51200    // [2kt][64]       half4 = 1024 B
#define B0O 52224    // 32 f32 (pre-scaled by log2e)
#define B1O 52352    // 128 f32
#define B2O 52864    // 128 f32
#define B3O 53376    // 32 f32
#define B4O 53504    // 16 f32
#define W5O 53568    // 16 f32 (pre-scaled)
#define LDS_SZ 53632 // 52.4 KB

__device__ __forceinline__ unsigned pk2(float a, float b) {
    union { fp16x2 h; unsigned u; } v;
    v.h = __builtin_amdgcn_cvt_pkrtz(a, b);
    return v.u;
}

// t-domain scaled selu: input t = log2e*x; output = log2e*act(x)
__device__ __forceinline__ float actt(float t) {
    float y = __builtin_fmaf(CA, exp2f(t), -CA);
    return t > 0.0f ? t : y;
}

// act + pack D-frag -> x16 B-frag (identical lane layouts)
__device__ __forceinline__ half4 pack4(f32x4 a) {
    union { unsigned u[2]; half4 h; } w;
    w.u[0] = pk2(actt(a[0]), actt(a[1]));
    w.u[1] = pk2(actt(a[2]), actt(a[3]));
    return w.h;
}

// VOLATILE LDS readers: defeat LICM. R7/R9 post-mortem: compiler hoists all
// loop-invariant weight-frag + bias LDS reads into ~190 arch VGPRs; uncapped
// that costs 1 wave/SIMD (R7), capped it spills 875MB to scratch (R9).
// Volatile forces per-use re-read; true loop live set ~90 regs -> fits 128.
__device__ __forceinline__ half4 ldsw4(const unsigned char* p) {
    return *(volatile const half4*)p;
}
__device__ __forceinline__ half8 ldsw8(const unsigned char* p) {
    return *(volatile const half8*)p;
}
__device__ __forceinline__ f32x4 ldsb4(const unsigned char* p) {
    return *(volatile const f32x4*)p;
}

extern "C" __global__ void __launch_bounds__(256, 2)
extractor_mlp_kernel(const float* __restrict__ x, const float* __restrict__ y,
                     const float* __restrict__ W0, const float* __restrict__ b0,
                     const float* __restrict__ W1, const float* __restrict__ b1,
                     const float* __restrict__ W2, const float* __restrict__ b2,
                     const float* __restrict__ W3, const float* __restrict__ b3,
                     const float* __restrict__ W4, const float* __restrict__ b4,
                     const float* __restrict__ W5, const float* __restrict__ b5,
                     float* __restrict__ out) {
    __shared__ __align__(16) unsigned char lds[LDS_SZ];
    const int tid = threadIdx.x;
    const int lane = tid & 63;
    const int wave = tid >> 6;
    const int r = lane & 15;
    const int g = lane >> 4;

    // ---------- stage fragment-linear weights (f16, scales folded) ----------
    // x16 A-frag: A[row = mt*16 + (l&15)][k = kt*16 + (l>>4)*4 + e] = W[k][row]
    for (int i = tid; i < 1024; i += 256) {      // W1 [32][128], scale s
        int l = i & 63, kt = (i >> 6) & 1, mt = i >> 7;
        const float* src = W1 + (kt * 16 + (l >> 4) * 4) * 128 + mt * 16 + (l & 15);
        half4 h;
#pragma unroll
        for (int e = 0; e < 4; ++e) h[e] = (_Float16)(src[e * 128] * SELU_SCALE);
        *(half4*)(lds + W1F + i * 8) = h;
    }
    for (int i = tid; i < 4096; i += 256) {      // W2 [128][128], scale s
        int l = i & 63, kt = (i >> 6) & 7, mt = i >> 9;
        const float* src = W2 + (kt * 16 + (l >> 4) * 4) * 128 + mt * 16 + (l & 15);
        half4 h;
#pragma unroll
        for (int e = 0; e < 4; ++e) h[e] = (_Float16)(src[e * 128] * SELU_SCALE);
        *(half4*)(lds + W2F + i * 8) = h;
    }
    for (int i = tid; i < 1024; i += 256) {      // W3 [128][32], scale s
        int l = i & 63, kt = (i >> 6) & 7, mt = i >> 9;
        const float* src = W3 + (kt * 16 + (l >> 4) * 4) * 32 + mt * 16 + (l & 15);
        half4 h;
#pragma unroll
        for (int e = 0; e < 4; ++e) h[e] = (_Float16)(src[e * 32] * SELU_SCALE);
        *(half4*)(lds + W3F + i * 8) = h;
    }
    // x32 A-frag for L0: k = (l>>4)*8 + e, zero-padded k>=6; scale log2e
    for (int i = tid; i < 128; i += 256) {       // W0F [2mt][64] half8
        int l = i & 63, mt = i >> 6;
        half8 h;
#pragma unroll
        for (int e = 0; e < 8; ++e) {
            int k = (l >> 4) * 8 + e;
            float v = (k < 6) ? W0[k * 32 + mt * 16 + (l & 15)] * LOG2E : 0.0f;
            h[e] = (_Float16)v;
        }
        *(half8*)(lds + W0F + i * 16) = h;
    }
    for (int i = tid; i < 128; i += 256) {       // W4F [2kt][64] half4, scale s
        int l = i & 63, kt = i >> 6;
        half4 h;
#pragma unroll
        for (int e = 0; e < 4; ++e)
            h[e] = (_Float16)(W4[(kt * 16 + (l >> 4) * 4 + e) * 16 + (l & 15)] * SELU_SCALE);
        *(half4*)(lds + W4F + i * 8) = h;
    }
    for (int i = tid; i < 32; i += 256)  ((float*)(lds + B0O))[i] = b0[i] * LOG2E;
    for (int i = tid; i < 128; i += 256) ((float*)(lds + B1O))[i] = b1[i] * LOG2E;
    for (int i = tid; i < 128; i += 256) ((float*)(lds + B2O))[i] = b2[i] * LOG2E;
    for (int i = tid; i < 32; i += 256)  ((float*)(lds + B3O))[i] = b3[i] * LOG2E;
    for (int i = tid; i < 16; i += 256)  ((float*)(lds + B4O))[i] = b4[i] * LOG2E;
    for (int i = tid; i < 16; i += 256)  ((float*)(lds + W5O))[i] = W5[i] * (SELU_SCALE * LN2f);
    const float b5v = b5[0];   // uniform -> SGPR

    __syncthreads();   // only barrier: weights ready

    // 1024 blocks x 1024 tokens; 64 blocks per image (65536 px)
    const int tbase = blockIdx.x * 1024 + wave * 256;
    const float* xb = x + (blockIdx.x >> 6) * 196608;
    const float* yb = y + (blockIdx.x >> 6) * 196608;
    const int pb = ((blockIdx.x & 63) << 10) + wave * 256 + r;

    // inputs kept PACKED (f16 pairs): 6 VGPRs
    unsigned cur[6], nxt[6];
#pragma unroll
    for (int nt = 0; nt < 2; ++nt) {
        cur[nt * 3 + 0] = pk2(xb[pb + nt * 16], xb[65536 + pb + nt * 16]);
        cur[nt * 3 + 1] = pk2(xb[131072 + pb + nt * 16], yb[pb + nt * 16]);
        cur[nt * 3 + 2] = pk2(yb[65536 + pb + nt * 16], yb[131072 + pb + nt * 16]);
    }

    const unsigned char* fbase = lds + lane * 8;    // b64 frag base
    const unsigned char* fbase16 = lds + lane * 16; // b128 frag base
    const unsigned char* bbase = lds + g * 16;      // bias base (per-g f32x4)

#pragma unroll 1
    for (int it = 0; it < 8; ++it) {
        // prefetch next iter's inputs (packed immediately) under this iter's compute
        if (it != 7) {
            const int p = pb + (it + 1) * 32;
#pragma unroll
            for (int nt = 0; nt < 2; ++nt) {
                nxt[nt * 3 + 0] = pk2(xb[p + nt * 16], xb[65536 + p + nt * 16]);
                nxt[nt * 3 + 1] = pk2(xb[131072 + p + nt * 16], yb[p + nt * 16]);
                nxt[nt * 3 + 2] = pk2(yb[65536 + p + nt * 16], yb[131072 + p + nt * 16]);
            }
        }

#pragma unroll
        for (int nt = 0; nt < 2; ++nt) {
            // ---- L0 (6->32, x32): input B-frag in regs, A-frag from LDS ----
            union { unsigned u[4]; half8 h; } hu;
            hu.u[0] = cur[nt * 3 + 0];
            hu.u[1] = cur[nt * 3 + 1];
            hu.u[2] = cur[nt * 3 + 2];
            hu.u[3] = 0;   // lanes g>=1 carry junk anyway: A-frag zeros cover
            f32x4 a0[2];
#pragma unroll
            for (int mt = 0; mt < 2; ++mt) {
                a0[mt] = ldsb4(bbase + B0O + mt * 64);
                half8 a = ldsw8(fbase16 + W0F + mt * 1024);
                a0[mt] = __builtin_amdgcn_mfma_f32_16x16x32_f16(a, hu.h, a0[mt], 0, 0, 0);
            }
            half4 p0[2] = { pack4(a0[0]), pack4(a0[1]) };

            // ---- L1 (32->128, x16): B from regs, A from LDS frags ----
            f32x4 a1[8];
#pragma unroll
            for (int mt = 0; mt < 8; ++mt)
                a1[mt] = ldsb4(bbase + B1O + mt * 64);
#pragma unroll
            for (int kt = 0; kt < 2; ++kt)
#pragma unroll
                for (int mt = 0; mt < 8; ++mt) {
                    half4 a = ldsw4(fbase + W1F + (mt * 2 + kt) * 512);
                    a1[mt] = __builtin_amdgcn_mfma_f32_16x16x16f16(a, p0[kt], a1[mt], 0, 0, 0);
                }
            half4 p1[8];
#pragma unroll
            for (int mt = 0; mt < 8; ++mt) p1[mt] = pack4(a1[mt]);

            // ---- L2 (128->128, x16): all-register handoff ----
            f32x4 a2[8];
#pragma unroll
            for (int mt = 0; mt < 8; ++mt)
                a2[mt] = ldsb4(bbase + B2O + mt * 64);
#pragma unroll
            for (int kt = 0; kt < 8; ++kt)
#pragma unroll
                for (int mt = 0; mt < 8; ++mt) {
                    half4 a = ldsw4(fbase + W2F + (mt * 8 + kt) * 512);
                    a2[mt] = __builtin_amdgcn_mfma_f32_16x16x16f16(a, p1[kt], a2[mt], 0, 0, 0);
                }
            half4 p2[8];
#pragma unroll
            for (int mt = 0; mt < 8; ++mt) p2[mt] = pack4(a2[mt]);

            // ---- L3 (128->32, x16) ----
            f32x4 a3[2];
#pragma unroll
            for (int mt = 0; mt < 2; ++mt)
                a3[mt] = ldsb4(bbase + B3O + mt * 64);
#pragma unroll
            for (int kt = 0; kt < 8; ++kt)
#pragma unroll
                for (int mt = 0; mt < 2; ++mt) {
                    half4 a = ldsw4(fbase + W3F + (mt * 8 + kt) * 512);
                    a3[mt] = __builtin_amdgcn_mfma_f32_16x16x16f16(a, p2[kt], a3[mt], 0, 0, 0);
                }
            half4 p3[2] = { pack4(a3[0]), pack4(a3[1]) };

            // ---- L4 (32->16, x16): A from LDS frags ----
            f32x4 a4 = ldsb4(bbase + B4O);
#pragma unroll
            for (int kt = 0; kt < 2; ++kt) {
                half4 a = ldsw4(fbase + W4F + kt * 512);
                a4 = __builtin_amdgcn_mfma_f32_16x16x16f16(a, p3[kt], a4, 0, 0, 0);
            }

            // ---- L5 (16->1): dot + cross-g reduce ----
            const f32x4 w5v = ldsb4(bbase + W5O);
            float d = 0.0f;
#pragma unroll
            for (int e = 0; e < 4; ++e) d += actt(a4[e]) * w5v[e];
            d += __shfl_xor(d, 16);
            d += __shfl_xor(d, 32);
            const float s = d + b5v;
            if (lane < 16) out[tbase + it * 32 + nt * 16 + lane] = s;
        }

#pragma unroll
        for (int i = 0; i < 6; ++i) cur[i] = nxt[i];
    }
}

extern "C" void kernel_launch(void* const* d_in, const int* in_sizes, int n_in,
                              void* d_out, int out_size, void* d_ws, size_t ws_size,
                              hipStream_t stream) {
    const float* x  = (const float*)d_in[0];
    const float* y  = (const float*)d_in[1];
    const float* W0 = (const float*)d_in[2];
    const float* b0 = (const float*)d_in[3];
    const float* W1 = (const float*)d_in[4];
    const float* b1 = (const float*)d_in[5];
    const float* W2 = (const float*)d_in[6];
    const float* b2 = (const float*)d_in[7];
    const float* W3 = (const float*)d_in[8];
    const float* b3 = (const float*)d_in[9];
    const float* W4 = (const float*)d_in[10];
    const float* b4 = (const float*)d_in[11];
    const float* W5 = (const float*)d_in[12];
    const float* b5 = (const float*)d_in[13];
    float* out = (float*)d_out;

    extractor_mlp_kernel<<<dim3(1024), dim3(256), 0, stream>>>(
        x, y, W0, b0, W1, b1, W2, b2, W3, b3, W4, b4, W5, b5, out);
}

// Round 11
// 132.985 us; speedup vs baseline: 3.8251x; 3.8251x over previous
//
#include <hip/hip_runtime.h>

typedef _Float16 half8 __attribute__((ext_vector_type(8)));
typedef _Float16 half4 __attribute__((ext_vector_type(4)));
typedef __fp16 fp16x2 __attribute__((ext_vector_type(2)));
typedef float f32x4 __attribute__((ext_vector_type(4)));

#define SELU_SCALE 1.0507009873554805f
#define SELU_ALPHA 1.6732632423543772f
#define LOG2E 1.4426950408889634f
#define LN2f 0.6931471805599453f
#define CA (SELU_ALPHA * LOG2E)

// ---- LDS: fragment-linear weights (conflict-free contiguous reads) ----
// b64 frag slot = (frag*64 + lane)*8 ; b128 slot = (frag*64 + lane)*16
#define W1F 0        // [8mt][2kt][64]  half4 = 8192 B
#define W2F 8192     // [8mt][8kt][64]  half4 = 32768 B
#define W3F 40960    // [2mt][8kt][64]  half4 = 8192 B
#define W0F 49152    // [2mt][64]       half8 = 2048 B
#define W4F 51200    // [2kt][64]       half4 = 1024 B
#define B0O 52224    // 32 f32 (pre-scaled by log2e)
#define B1O 52352    // 128 f32
#define B2O 52864    // 128 f32
#define B3O 53376    // 32 f32
#define B4O 53504    // 16 f32
#define W5O 53568    // 16 f32 (pre-scaled)
#define LDS_SZ 53632 // 53632*3 = 160896 <= 163840 -> 3 blocks/CU

__device__ __forceinline__ unsigned pk2(float a, float b) {
    union { fp16x2 h; unsigned u; } v;
    v.h = __builtin_amdgcn_cvt_pkrtz(a, b);
    return v.u;
}

// t-domain scaled selu: input t = log2e*x; output = log2e*act(x)
__device__ __forceinline__ float actt(float t) {
    float y = __builtin_fmaf(CA, exp2f(t), -CA);
    return t > 0.0f ? t : y;
}

// act + pack D-frag -> x16 B-frag (identical lane layouts)
__device__ __forceinline__ half4 pack4(f32x4 a) {
    union { unsigned u[2]; half4 h; } w;
    w.u[0] = pk2(actt(a[0]), actt(a[1]));
    w.u[1] = pk2(actt(a[2]), actt(a[3]));
    return w.h;
}

// Register model (R7-R10 evidence): AGPR arrays are allocated WITHOUT
// cross-layer reuse (R8: 21 f32x4 = 84 acc regs). Fix: ONE acc[8] reused
// by every layer (32 acc). LICM fix: asm memory clobber at pass top keeps
// weight/bias LDS reads inside the loop (R7's 188-arch hoard) while
// allowing intra-pass batching (R10's volatile serialized -> 508us).
// (256,3): total cap ~170/wave; lean live set ~110 fits -> 3 waves/SIMD.
extern "C" __global__ void __launch_bounds__(256, 3)
extractor_mlp_kernel(const float* __restrict__ x, const float* __restrict__ y,
                     const float* __restrict__ W0, const float* __restrict__ b0,
                     const float* __restrict__ W1, const float* __restrict__ b1,
                     const float* __restrict__ W2, const float* __restrict__ b2,
                     const float* __restrict__ W3, const float* __restrict__ b3,
                     const float* __restrict__ W4, const float* __restrict__ b4,
                     const float* __restrict__ W5, const float* __restrict__ b5,
                     float* __restrict__ out) {
    __shared__ __align__(16) unsigned char lds[LDS_SZ];
    const int tid = threadIdx.x;
    const int lane = tid & 63;
    const int wave = tid >> 6;
    const int r = lane & 15;
    const int g = lane >> 4;

    // ---------- stage fragment-linear weights (f16, scales folded) ----------
    // x16 A-frag: A[row = mt*16 + (l&15)][k = kt*16 + (l>>4)*4 + e] = W[k][row]
    for (int i = tid; i < 1024; i += 256) {      // W1 [32][128], scale s
        int l = i & 63, kt = (i >> 6) & 1, mt = i >> 7;
        const float* src = W1 + (kt * 16 + (l >> 4) * 4) * 128 + mt * 16 + (l & 15);
        half4 h;
#pragma unroll
        for (int e = 0; e < 4; ++e) h[e] = (_Float16)(src[e * 128] * SELU_SCALE);
        *(half4*)(lds + W1F + i * 8) = h;
    }
    for (int i = tid; i < 4096; i += 256) {      // W2 [128][128], scale s
        int l = i & 63, kt = (i >> 6) & 7, mt = i >> 9;
        const float* src = W2 + (kt * 16 + (l >> 4) * 4) * 128 + mt * 16 + (l & 15);
        half4 h;
#pragma unroll
        for (int e = 0; e < 4; ++e) h[e] = (_Float16)(src[e * 128] * SELU_SCALE);
        *(half4*)(lds + W2F + i * 8) = h;
    }
    for (int i = tid; i < 1024; i += 256) {      // W3 [128][32], scale s
        int l = i & 63, kt = (i >> 6) & 7, mt = i >> 9;
        const float* src = W3 + (kt * 16 + (l >> 4) * 4) * 32 + mt * 16 + (l & 15);
        half4 h;
#pragma unroll
        for (int e = 0; e < 4; ++e) h[e] = (_Float16)(src[e * 32] * SELU_SCALE);
        *(half4*)(lds + W3F + i * 8) = h;
    }
    // x32 A-frag for L0: k = (l>>4)*8 + e, zero-padded k>=6; scale log2e
    for (int i = tid; i < 128; i += 256) {       // W0F [2mt][64] half8
        int l = i & 63, mt = i >> 6;
        half8 h;
#pragma unroll
        for (int e = 0; e < 8; ++e) {
            int k = (l >> 4) * 8 + e;
            float v = (k < 6) ? W0[k * 32 + mt * 16 + (l & 15)] * LOG2E : 0.0f;
            h[e] = (_Float16)v;
        }
        *(half8*)(lds + W0F + i * 16) = h;
    }
    for (int i = tid; i < 128; i += 256) {       // W4F [2kt][64] half4, scale s
        int l = i & 63, kt = i >> 6;
        half4 h;
#pragma unroll
        for (int e = 0; e < 4; ++e)
            h[e] = (_Float16)(W4[(kt * 16 + (l >> 4) * 4 + e) * 16 + (l & 15)] * SELU_SCALE);
        *(half4*)(lds + W4F + i * 8) = h;
    }
    for (int i = tid; i < 32; i += 256)  ((float*)(lds + B0O))[i] = b0[i] * LOG2E;
    for (int i = tid; i < 128; i += 256) ((float*)(lds + B1O))[i] = b1[i] * LOG2E;
    for (int i = tid; i < 128; i += 256) ((float*)(lds + B2O))[i] = b2[i] * LOG2E;
    for (int i = tid; i < 32; i += 256)  ((float*)(lds + B3O))[i] = b3[i] * LOG2E;
    for (int i = tid; i < 16; i += 256)  ((float*)(lds + B4O))[i] = b4[i] * LOG2E;
    for (int i = tid; i < 16; i += 256)  ((float*)(lds + W5O))[i] = W5[i] * (SELU_SCALE * LN2f);
    const float b5v = b5[0];   // uniform -> SGPR

    __syncthreads();   // only barrier: weights ready

    // 1024 blocks x 1024 tokens; 64 blocks per image (65536 px)
    // pass it: wave w handles tokens block*1024 + it*64 + w*16 .. +16
    const int tbase = blockIdx.x * 1024;
    const float* xb = x + (blockIdx.x >> 6) * 196608;
    const float* yb = y + (blockIdx.x >> 6) * 196608;
    const int pb = ((blockIdx.x & 63) << 10) + wave * 16 + r;

    const unsigned char* fbase = lds + lane * 8;    // b64 frag base
    const unsigned char* fbase16 = lds + lane * 16; // b128 frag base
    const unsigned char* bbase = lds + g * 16;      // bias base (per-g f32x4)

#pragma unroll 1
    for (int it = 0; it < 16; ++it) {
        asm volatile("" ::: "memory");   // LICM fence: LDS reads stay in-loop
        const int p = pb + it * 64;

        // ---- inputs: 6 scalar loads, packed immediately (3 VGPRs) ----
        union { unsigned u[4]; half8 h; } hu;
        hu.u[0] = pk2(xb[p], xb[65536 + p]);
        hu.u[1] = pk2(xb[131072 + p], yb[p]);
        hu.u[2] = pk2(yb[65536 + p], yb[131072 + p]);
        hu.u[3] = 0;   // lanes g>=1 carry junk anyway: A-frag zeros cover

        f32x4 acc[8];   // ONE accumulator array reused by every layer

        // ---- L0 (6->32, x32) ----
        half4 p0[2];
#pragma unroll
        for (int mt = 0; mt < 2; ++mt) {
            acc[mt] = *(const f32x4*)(bbase + B0O + mt * 64);
            half8 a = *(const half8*)(fbase16 + W0F + mt * 1024);
            acc[mt] = __builtin_amdgcn_mfma_f32_16x16x32_f16(a, hu.h, acc[mt], 0, 0, 0);
        }
        p0[0] = pack4(acc[0]);
        p0[1] = pack4(acc[1]);

        // ---- L1 (32->128, x16): B from regs ----
#pragma unroll
        for (int mt = 0; mt < 8; ++mt)
            acc[mt] = *(const f32x4*)(bbase + B1O + mt * 64);
#pragma unroll
        for (int kt = 0; kt < 2; ++kt)
#pragma unroll
            for (int mt = 0; mt < 8; ++mt) {
                half4 a = *(const half4*)(fbase + W1F + (mt * 2 + kt) * 512);
                acc[mt] = __builtin_amdgcn_mfma_f32_16x16x16f16(a, p0[kt], acc[mt], 0, 0, 0);
            }
        half4 pp[8];
#pragma unroll
        for (int mt = 0; mt < 8; ++mt) pp[mt] = pack4(acc[mt]);

        // ---- L2 (128->128, x16): all-register handoff ----
#pragma unroll
        for (int mt = 0; mt < 8; ++mt)
            acc[mt] = *(const f32x4*)(bbase + B2O + mt * 64);
#pragma unroll
        for (int kt = 0; kt < 8; ++kt)
#pragma unroll
            for (int mt = 0; mt < 8; ++mt) {
                half4 a = *(const half4*)(fbase + W2F + (mt * 8 + kt) * 512);
                acc[mt] = __builtin_amdgcn_mfma_f32_16x16x16f16(a, pp[kt], acc[mt], 0, 0, 0);
            }
#pragma unroll
        for (int mt = 0; mt < 8; ++mt) pp[mt] = pack4(acc[mt]);   // reuse pp

        // ---- L3 (128->32, x16) ----
#pragma unroll
        for (int mt = 0; mt < 2; ++mt)
            acc[mt] = *(const f32x4*)(bbase + B3O + mt * 64);
#pragma unroll
        for (int kt = 0; kt < 8; ++kt)
#pragma unroll
            for (int mt = 0; mt < 2; ++mt) {
                half4 a = *(const half4*)(fbase + W3F + (mt * 8 + kt) * 512);
                acc[mt] = __builtin_amdgcn_mfma_f32_16x16x16f16(a, pp[kt], acc[mt], 0, 0, 0);
            }
        p0[0] = pack4(acc[0]);   // reuse p0 as L3 output
        p0[1] = pack4(acc[1]);

        // ---- L4 (32->16, x16) ----
        acc[0] = *(const f32x4*)(bbase + B4O);
#pragma unroll
        for (int kt = 0; kt < 2; ++kt) {
            half4 a = *(const half4*)(fbase + W4F + kt * 512);
            acc[0] = __builtin_amdgcn_mfma_f32_16x16x16f16(a, p0[kt], acc[0], 0, 0, 0);
        }

        // ---- L5 (16->1): dot + cross-g reduce ----
        const f32x4 w5v = *(const f32x4*)(bbase + W5O);
        float d = 0.0f;
#pragma unroll
        for (int e = 0; e < 4; ++e) d += actt(acc[0][e]) * w5v[e];
        d += __shfl_xor(d, 16);
        d += __shfl_xor(d, 32);
        const float s = d + b5v;
        if (lane < 16) out[tbase + it * 64 + wave * 16 + lane] = s;
    }
}

extern "C" void kernel_launch(void* const* d_in, const int* in_sizes, int n_in,
                              void* d_out, int out_size, void* d_ws, size_t ws_size,
                              hipStream_t stream) {
    const float* x  = (const float*)d_in[0];
    const float* y  = (const float*)d_in[1];
    const float* W0 = (const float*)d_in[2];
    const float* b0 = (const float*)d_in[3];
    const float* W1 = (const float*)d_in[4];
    const float* b1 = (const float*)d_in[5];
    const float* W2 = (const float*)d_in[6];
    const float* b2 = (const float*)d_in[7];
    const float* W3 = (const float*)d_in[8];
    const float* b3 = (const float*)d_in[9];
    const float* W4 = (const float*)d_in[10];
    const float* b4 = (const float*)d_in[11];
    const float* W5 = (const float*)d_in[12];
    const float* b5 = (const float*)d_in[13];
    float* out = (float*)d_out;

    extractor_mlp_kernel<<<dim3(1024), dim3(256), 0, stream>>>(
        x, y, W0, b0, W1, b1, W2, b2, W3, b3, W4, b4, W5, b5, out);
}

// Round 12
// 127.828 us; speedup vs baseline: 3.9794x; 1.0403x over previous
//
#include <hip/hip_runtime.h>

typedef _Float16 half8 __attribute__((ext_vector_type(8)));
typedef _Float16 half4 __attribute__((ext_vector_type(4)));
typedef __fp16 fp16x2 __attribute__((ext_vector_type(2)));
typedef float f32x4 __attribute__((ext_vector_type(4)));

#define SELU_SCALE 1.0507009873554805f
#define SELU_ALPHA 1.6732632423543772f
#define LOG2E 1.4426950408889634f
#define LN2f 0.6931471805599453f
#define CA (SELU_ALPHA * LOG2E)

// ---- LDS: fragment-linear weights (conflict-free contiguous reads) ----
// b64 frag slot = (frag*64 + lane)*8 ; b128 slot = (frag*64 + lane)*16
#define W1F 0        // [8mt][2kt][64]  half4 = 8192 B
#define W2F 8192     // [8mt][8kt][64]  half4 = 32768 B
#define W3F 40960    // [2mt][8kt][64]  half4 = 8192 B
#define W0F 49152    // [2mt][64]       half8 = 2048 B
#define W4F 51200    // [2kt][64]       half4 = 1024 B
#define B0O 52224    // 32 f32 (pre-scaled by log2e)
#define B1O 52352    // 128 f32
#define B2O 52864    // 128 f32
#define B3O 53376    // 32 f32
#define B4O 53504    // 16 f32
#define W5O 53568    // 16 f32 (pre-scaled)
#define LDS_SZ 53632 // x2 blocks = 107KB/CU -> 2 blocks x 8 waves = 16 waves/CU

__device__ __forceinline__ unsigned pk2(float a, float b) {
    union { fp16x2 h; unsigned u; } v;
    v.h = __builtin_amdgcn_cvt_pkrtz(a, b);
    return v.u;
}

// t-domain scaled selu: input t = log2e*x; output = log2e*act(x)
__device__ __forceinline__ float actt(float t) {
    float y = __builtin_fmaf(CA, exp2f(t), -CA);
    return t > 0.0f ? t : y;
}

// act + pack D-frag -> x16 B-frag (identical lane layouts)
__device__ __forceinline__ half4 pack4(f32x4 a) {
    union { unsigned u[2]; half4 h; } w;
    w.u[0] = pk2(actt(a[0]), actt(a[1]));
    w.u[1] = pk2(actt(a[2]), actt(a[3]));
    return w.h;
}

// R11 proved: single acc[8] reuse + asm LICM fence -> 72 VGPR, zero spill,
// FETCH exactly ideal. R12 single change: 512-thr blocks, (512,2) -> cap 128
// >= ~104 live set, 2 blocks/CU x 8 waves = 4 waves/SIMD (R11 was ~2).
extern "C" __global__ void __launch_bounds__(512, 2)
extractor_mlp_kernel(const float* __restrict__ x, const float* __restrict__ y,
                     const float* __restrict__ W0, const float* __restrict__ b0,
                     const float* __restrict__ W1, const float* __restrict__ b1,
                     const float* __restrict__ W2, const float* __restrict__ b2,
                     const float* __restrict__ W3, const float* __restrict__ b3,
                     const float* __restrict__ W4, const float* __restrict__ b4,
                     const float* __restrict__ W5, const float* __restrict__ b5,
                     float* __restrict__ out) {
    __shared__ __align__(16) unsigned char lds[LDS_SZ];
    const int tid = threadIdx.x;
    const int lane = tid & 63;
    const int wave = tid >> 6;
    const int r = lane & 15;
    const int g = lane >> 4;

    // ---------- stage fragment-linear weights (f16, scales folded) ----------
    // x16 A-frag: A[row = mt*16 + (l&15)][k = kt*16 + (l>>4)*4 + e] = W[k][row]
    for (int i = tid; i < 1024; i += 512) {      // W1 [32][128], scale s
        int l = i & 63, kt = (i >> 6) & 1, mt = i >> 7;
        const float* src = W1 + (kt * 16 + (l >> 4) * 4) * 128 + mt * 16 + (l & 15);
        half4 h;
#pragma unroll
        for (int e = 0; e < 4; ++e) h[e] = (_Float16)(src[e * 128] * SELU_SCALE);
        *(half4*)(lds + W1F + i * 8) = h;
    }
    for (int i = tid; i < 4096; i += 512) {      // W2 [128][128], scale s
        int l = i & 63, kt = (i >> 6) & 7, mt = i >> 9;
        const float* src = W2 + (kt * 16 + (l >> 4) * 4) * 128 + mt * 16 + (l & 15);
        half4 h;
#pragma unroll
        for (int e = 0; e < 4; ++e) h[e] = (_Float16)(src[e * 128] * SELU_SCALE);
        *(half4*)(lds + W2F + i * 8) = h;
    }
    for (int i = tid; i < 1024; i += 512) {      // W3 [128][32], scale s
        int l = i & 63, kt = (i >> 6) & 7, mt = i >> 9;
        const float* src = W3 + (kt * 16 + (l >> 4) * 4) * 32 + mt * 16 + (l & 15);
        half4 h;
#pragma unroll
        for (int e = 0; e < 4; ++e) h[e] = (_Float16)(src[e * 32] * SELU_SCALE);
        *(half4*)(lds + W3F + i * 8) = h;
    }
    // x32 A-frag for L0: k = (l>>4)*8 + e, zero-padded k>=6; scale log2e
    for (int i = tid; i < 128; i += 512) {       // W0F [2mt][64] half8
        int l = i & 63, mt = i >> 6;
        half8 h;
#pragma unroll
        for (int e = 0; e < 8; ++e) {
            int k = (l >> 4) * 8 + e;
            float v = (k < 6) ? W0[k * 32 + mt * 16 + (l & 15)] * LOG2E : 0.0f;
            h[e] = (_Float16)v;
        }
        *(half8*)(lds + W0F + i * 16) = h;
    }
    for (int i = tid; i < 128; i += 512) {       // W4F [2kt][64] half4, scale s
        int l = i & 63, kt = i >> 6;
        half4 h;
#pragma unroll
        for (int e = 0; e < 4; ++e)
            h[e] = (_Float16)(W4[(kt * 16 + (l >> 4) * 4 + e) * 16 + (l & 15)] * SELU_SCALE);
        *(half4*)(lds + W4F + i * 8) = h;
    }
    for (int i = tid; i < 32; i += 512)  ((float*)(lds + B0O))[i] = b0[i] * LOG2E;
    for (int i = tid; i < 128; i += 512) ((float*)(lds + B1O))[i] = b1[i] * LOG2E;
    for (int i = tid; i < 128; i += 512) ((float*)(lds + B2O))[i] = b2[i] * LOG2E;
    for (int i = tid; i < 32; i += 512)  ((float*)(lds + B3O))[i] = b3[i] * LOG2E;
    for (int i = tid; i < 16; i += 512)  ((float*)(lds + B4O))[i] = b4[i] * LOG2E;
    for (int i = tid; i < 16; i += 512)  ((float*)(lds + W5O))[i] = W5[i] * (SELU_SCALE * LN2f);
    const float b5v = b5[0];   // uniform -> SGPR

    __syncthreads();   // only barrier: weights ready

    // 512 blocks x 2048 tokens; 32 blocks per image (65536 px)
    // pass it: wave w handles tokens block*2048 + it*128 + w*16 .. +16
    const int tbase = blockIdx.x * 2048;
    const float* xb = x + (blockIdx.x >> 5) * 196608;
    const float* yb = y + (blockIdx.x >> 5) * 196608;
    const int pb = ((blockIdx.x & 31) << 11) + wave * 16 + r;

    const unsigned char* fbase = lds + lane * 8;    // b64 frag base
    const unsigned char* fbase16 = lds + lane * 16; // b128 frag base
    const unsigned char* bbase = lds + g * 16;      // bias base (per-g f32x4)

#pragma unroll 1
    for (int it = 0; it < 16; ++it) {
        asm volatile("" ::: "memory");   // LICM fence: LDS reads stay in-loop
        const int p = pb + it * 128;

        // ---- inputs: 6 scalar loads, packed immediately (3 VGPRs) ----
        union { unsigned u[4]; half8 h; } hu;
        hu.u[0] = pk2(xb[p], xb[65536 + p]);
        hu.u[1] = pk2(xb[131072 + p], yb[p]);
        hu.u[2] = pk2(yb[65536 + p], yb[131072 + p]);
        hu.u[3] = 0;   // lanes g>=1 carry junk anyway: A-frag zeros cover

        f32x4 acc[8];   // ONE accumulator array reused by every layer

        // ---- L0 (6->32, x32) ----
        half4 p0[2];
#pragma unroll
        for (int mt = 0; mt < 2; ++mt) {
            acc[mt] = *(const f32x4*)(bbase + B0O + mt * 64);
            half8 a = *(const half8*)(fbase16 + W0F + mt * 1024);
            acc[mt] = __builtin_amdgcn_mfma_f32_16x16x32_f16(a, hu.h, acc[mt], 0, 0, 0);
        }
        p0[0] = pack4(acc[0]);
        p0[1] = pack4(acc[1]);

        // ---- L1 (32->128, x16): B from regs ----
#pragma unroll
        for (int mt = 0; mt < 8; ++mt)
            acc[mt] = *(const f32x4*)(bbase + B1O + mt * 64);
#pragma unroll
        for (int kt = 0; kt < 2; ++kt)
#pragma unroll
            for (int mt = 0; mt < 8; ++mt) {
                half4 a = *(const half4*)(fbase + W1F + (mt * 2 + kt) * 512);
                acc[mt] = __builtin_amdgcn_mfma_f32_16x16x16f16(a, p0[kt], acc[mt], 0, 0, 0);
            }
        half4 pp[8];
#pragma unroll
        for (int mt = 0; mt < 8; ++mt) pp[mt] = pack4(acc[mt]);

        // ---- L2 (128->128, x16): all-register handoff ----
#pragma unroll
        for (int mt = 0; mt < 8; ++mt)
            acc[mt] = *(const f32x4*)(bbase + B2O + mt * 64);
#pragma unroll
        for (int kt = 0; kt < 8; ++kt)
#pragma unroll
            for (int mt = 0; mt < 8; ++mt) {
                half4 a = *(const half4*)(fbase + W2F + (mt * 8 + kt) * 512);
                acc[mt] = __builtin_amdgcn_mfma_f32_16x16x16f16(a, pp[kt], acc[mt], 0, 0, 0);
            }
#pragma unroll
        for (int mt = 0; mt < 8; ++mt) pp[mt] = pack4(acc[mt]);   // reuse pp

        // ---- L3 (128->32, x16) ----
#pragma unroll
        for (int mt = 0; mt < 2; ++mt)
            acc[mt] = *(const f32x4*)(bbase + B3O + mt * 64);
#pragma unroll
        for (int kt = 0; kt < 8; ++kt)
#pragma unroll
            for (int mt = 0; mt < 2; ++mt) {
                half4 a = *(const half4*)(fbase + W3F + (mt * 8 + kt) * 512);
                acc[mt] = __builtin_amdgcn_mfma_f32_16x16x16f16(a, pp[kt], acc[mt], 0, 0, 0);
            }
        p0[0] = pack4(acc[0]);   // reuse p0 as L3 output
        p0[1] = pack4(acc[1]);

        // ---- L4 (32->16, x16) ----
        acc[0] = *(const f32x4*)(bbase + B4O);
#pragma unroll
        for (int kt = 0; kt < 2; ++kt) {
            half4 a = *(const half4*)(fbase + W4F + kt * 512);
            acc[0] = __builtin_amdgcn_mfma_f32_16x16x16f16(a, p0[kt], acc[0], 0, 0, 0);
        }

        // ---- L5 (16->1): dot + cross-g reduce ----
        const f32x4 w5v = *(const f32x4*)(bbase + W5O);
        float d = 0.0f;
#pragma unroll
        for (int e = 0; e < 4; ++e) d += actt(acc[0][e]) * w5v[e];
        d += __shfl_xor(d, 16);
        d += __shfl_xor(d, 32);
        const float s = d + b5v;
        if (lane < 16) out[tbase + it * 128 + wave * 16 + lane] = s;
    }
}

extern "C" void kernel_launch(void* const* d_in, const int* in_sizes, int n_in,
                              void* d_out, int out_size, void* d_ws, size_t ws_size,
                              hipStream_t stream) {
    const float* x  = (const float*)d_in[0];
    const float* y  = (const float*)d_in[1];
    const float* W0 = (const float*)d_in[2];
    const float* b0 = (const float*)d_in[3];
    const float* W1 = (const float*)d_in[4];
    const float* b1 = (const float*)d_in[5];
    const float* W2 = (const float*)d_in[6];
    const float* b2 = (const float*)d_in[7];
    const float* W3 = (const float*)d_in[8];
    const float* b3 = (const float*)d_in[9];
    const float* W4 = (const float*)d_in[10];
    const float* b4 = (const float*)d_in[11];
    const float* W5 = (const float*)d_in[12];
    const float* b5 = (const float*)d_in[13];
    float* out = (float*)d_out;

    extractor_mlp_kernel<<<dim3(512), dim3(512), 0, stream>>>(
        x, y, W0, b0, W1, b1, W2, b2, W3, b3, W4, b4, W5, b5, out);
}